// Round 3
// baseline (5768.648 us; speedup 1.0000x reference)
//
#include <hip/hip_runtime.h>
#include <hip/hip_bf16.h>

#define SEQ 2048
#define NB  64

typedef _Float16 f16x8 __attribute__((ext_vector_type(8)));
typedef _Float16 f16x4 __attribute__((ext_vector_type(4)));
typedef float    f32x4 __attribute__((ext_vector_type(4)));

__device__ __forceinline__ float fast_sigmoid(float x) {
    float e = __builtin_amdgcn_exp2f(-1.4426950408889634f * x);
    return __builtin_amdgcn_rcpf(1.f + e);
}
__device__ __forceinline__ float fast_tanh(float x) {
    float e = __builtin_amdgcn_exp2f(2.8853900817779268f * x);
    return fmaf(-2.f, __builtin_amdgcn_rcpf(1.f + e), 1.f);
}

// Split f32 -> (hi, lo) f16 pair: hi+lo carries ~22 mantissa bits.
__global__ __launch_bounds__(256) void split_f32(
    const float* __restrict__ s, _Float16* __restrict__ hi,
    _Float16* __restrict__ lo, int n)
{
    int i = blockIdx.x * 256 + threadIdx.x;
    if (i < n) {
        float v = s[i];
        _Float16 h = (_Float16)v;
        hi[i] = h;
        lo[i] = (_Float16)(v - (float)h);
    }
}

// ---------------------------------------------------------------------------
// Layer-0 input GEMM (K=64). A = x (f32, split on the fly), W pre-split f16.
// gx[s*64+b][dir*512+n] = sum_k x[t*NB+b][k]*W[n][k] + bias[n]   (f32 out)
// dir1 slots time-reversed: t = SEQ-1-tq0-s. Wave = 16M x 64N, mfma 16x16x32.
// grid = (8, Tc, 2); x-major dispatch keeps the A-slice L2-hot across N-blocks.
// ---------------------------------------------------------------------------
__global__ __launch_bounds__(256) void gemm0(
    const float* __restrict__ x,
    const _Float16* __restrict__ whi_f, const _Float16* __restrict__ wlo_f,
    const _Float16* __restrict__ whi_r, const _Float16* __restrict__ wlo_r,
    const float* __restrict__ bf_, const float* __restrict__ br_,
    float* __restrict__ gx, int tq0)
{
    const int lane = threadIdx.x & 63, wave = threadIdx.x >> 6;
    const int dir  = blockIdx.z;
    const _Float16* Whi = dir ? whi_r : whi_f;
    const _Float16* Wlo = dir ? wlo_r : wlo_f;
    const float* bias   = dir ? br_   : bf_;
    const int s   = blockIdx.y;
    const int t   = dir ? (SEQ - 1 - tq0 - s) : (tq0 + s);
    const int m0  = s * 64 + wave * 16;      // local gx row base
    const int n0  = blockIdx.x * 64;
    const int col = lane & 15, kg = lane >> 4;

    f16x8 Bhi[4][2], Blo[4][2];
    #pragma unroll
    for (int nt = 0; nt < 4; ++nt)
        #pragma unroll
        for (int ks = 0; ks < 2; ++ks) {
            size_t idx = (size_t)(n0 + nt*16 + col) * 64 + ks*32 + kg*8;
            Bhi[nt][ks] = *(const f16x8*)(Whi + idx);
            Blo[nt][ks] = *(const f16x8*)(Wlo + idx);
        }
    f32x4 acc[4] = {{0,0,0,0},{0,0,0,0},{0,0,0,0},{0,0,0,0}};
    #pragma unroll
    for (int ks = 0; ks < 2; ++ks) {
        const float* ar = x + ((size_t)t*NB + wave*16 + col) * 64 + ks*32 + kg*8;
        float4 a0 = *(const float4*)ar;
        float4 a1 = *(const float4*)(ar + 4);
        f16x8 ahi, alo;
        float av[8] = {a0.x,a0.y,a0.z,a0.w,a1.x,a1.y,a1.z,a1.w};
        #pragma unroll
        for (int e = 0; e < 8; ++e) {
            _Float16 h = (_Float16)av[e];
            ahi[e] = h; alo[e] = (_Float16)(av[e] - (float)h);
        }
        #pragma unroll
        for (int nt = 0; nt < 4; ++nt) {
            acc[nt] = __builtin_amdgcn_mfma_f32_16x16x32_f16(ahi, Bhi[nt][ks], acc[nt], 0,0,0);
            acc[nt] = __builtin_amdgcn_mfma_f32_16x16x32_f16(ahi, Blo[nt][ks], acc[nt], 0,0,0);
            acc[nt] = __builtin_amdgcn_mfma_f32_16x16x32_f16(alo, Bhi[nt][ks], acc[nt], 0,0,0);
        }
    }
    // C layout: col = lane&15 (N), row = kg*4 + r (M)
    #pragma unroll
    for (int nt = 0; nt < 4; ++nt) {
        const int n = n0 + nt*16 + col;
        const float bv = bias[n];
        #pragma unroll
        for (int r = 0; r < 4; ++r) {
            const int row = m0 + kg*4 + r;
            gx[(size_t)row * 1024 + dir*512 + n] = acc[nt][r] + bv;
        }
    }
}

// ---------------------------------------------------------------------------
// Layer-1 input GEMM (K=256). A = h0 as pre-split f16 hi/lo pair. Wave = 32Mx32N.
// grid = (8, Tc, 2).
// ---------------------------------------------------------------------------
template<int SPLIT_A>
__global__ __launch_bounds__(256) void gemm1(
    const _Float16* __restrict__ Ahi, const _Float16* __restrict__ Alo,
    const _Float16* __restrict__ whi_f, const _Float16* __restrict__ wlo_f,
    const _Float16* __restrict__ whi_r, const _Float16* __restrict__ wlo_r,
    const float* __restrict__ bf_, const float* __restrict__ br_,
    float* __restrict__ gx, int tq0)
{
    const int lane = threadIdx.x & 63, wave = threadIdx.x >> 6;
    const int dir  = blockIdx.z;
    const _Float16* Whi = dir ? whi_r : whi_f;
    const _Float16* Wlo = dir ? wlo_r : wlo_f;
    const float* bias   = dir ? br_   : bf_;
    const int wm = wave >> 1, wn = wave & 1;
    const int s  = blockIdx.y;
    const int t  = dir ? (SEQ - 1 - tq0 - s) : (tq0 + s);
    const int n0 = blockIdx.x * 64 + wn * 32;
    const int col = lane & 15, kg = lane >> 4;

    f16x8 Bhi[2][8], Blo[2][8];
    #pragma unroll
    for (int nt = 0; nt < 2; ++nt)
        #pragma unroll
        for (int ks = 0; ks < 8; ++ks) {
            size_t idx = (size_t)(n0 + nt*16 + col) * 256 + ks*32 + kg*8;
            Bhi[nt][ks] = *(const f16x8*)(Whi + idx);
            Blo[nt][ks] = *(const f16x8*)(Wlo + idx);
        }
    f32x4 acc[2][2] = {{{0,0,0,0},{0,0,0,0}},{{0,0,0,0},{0,0,0,0}}};
    #pragma unroll
    for (int ks = 0; ks < 8; ++ks) {
        #pragma unroll
        for (int mt = 0; mt < 2; ++mt) {
            const size_t arow = (size_t)t*NB + wm*32 + mt*16 + col;
            f16x8 ahi = *(const f16x8*)(Ahi + arow*256 + ks*32 + kg*8);
            f16x8 alo;
            if constexpr (SPLIT_A) alo = *(const f16x8*)(Alo + arow*256 + ks*32 + kg*8);
            #pragma unroll
            for (int nt = 0; nt < 2; ++nt) {
                acc[mt][nt] = __builtin_amdgcn_mfma_f32_16x16x32_f16(ahi, Bhi[nt][ks], acc[mt][nt], 0,0,0);
                acc[mt][nt] = __builtin_amdgcn_mfma_f32_16x16x32_f16(ahi, Blo[nt][ks], acc[mt][nt], 0,0,0);
                if constexpr (SPLIT_A)
                    acc[mt][nt] = __builtin_amdgcn_mfma_f32_16x16x32_f16(alo, Bhi[nt][ks], acc[mt][nt], 0,0,0);
            }
        }
    }
    #pragma unroll
    for (int mt = 0; mt < 2; ++mt)
        #pragma unroll
        for (int nt = 0; nt < 2; ++nt) {
            const int n = n0 + nt*16 + col;
            const float bv = bias[n];
            #pragma unroll
            for (int r = 0; r < 4; ++r) {
                const int row = s*64 + wm*32 + mt*16 + kg*4 + r;
                gx[(size_t)row * 1024 + dir*512 + n] = acc[mt][nt][r] + bv;
            }
        }
}

// ---------------------------------------------------------------------------
// Recurrence over one time-chunk. One WG per (b, dir), 512 threads.
// Thread j owns gate-row j of w_hh (128 f32 in VGPRs). gx is f32.
// OMODE 0: write h as f16 hi/lo pair (feeds layer-1 GEMM). OMODE 1: f16 only.
// ---------------------------------------------------------------------------
template<int OMODE>
__global__ __launch_bounds__(512) void lstm_rec(
    const float* __restrict__ gx,        // [Tc*NB][1024] chunk-local, f32
    const float* __restrict__ Whf, const float* __restrict__ Whr,
    _Float16* __restrict__ o1, _Float16* __restrict__ o2,
    float* __restrict__ state, int tq0, int steps, int first)
{
    const int b   = blockIdx.x;
    const int dir = blockIdx.y;
    const float* Wh = dir ? Whr : Whf;
    const int j = threadIdx.x;

    float w[128];
    {
        const float4* wr = (const float4*)(Wh + (size_t)j * 128);
        #pragma unroll
        for (int q = 0; q < 32; ++q) {
            float4 v = wr[q];
            w[4*q+0]=v.x; w[4*q+1]=v.y; w[4*q+2]=v.z; w[4*q+3]=v.w;
        }
    }

    __shared__ float hsh[128];
    __shared__ float ash[512];   // [k][4] = i,f,g,o
    float* st = state + ((size_t)dir*NB + b) * 256;
    if (j < 128) hsh[j] = first ? 0.f : st[j];
    float c = (j < 128) ? (first ? 0.f : st[128 + j]) : 0.f;
    const int type = j >> 7;
    const int k    = j & 127;
    __syncthreads();

    float gcur = gx[((size_t)b)*1024 + dir*512 + j];

    for (int step = 0; step < steps; ++step) {
        float gnext = 0.f;
        if (step + 1 < steps)
            gnext = gx[((size_t)(step+1)*NB + b)*1024 + dir*512 + j];
        float acc = gcur;
        #pragma unroll
        for (int q = 0; q < 32; ++q) {
            float4 h4 = *(const float4*)(hsh + 4*q);   // uniform addr -> broadcast
            acc = fmaf(h4.x, w[4*q+0], acc);
            acc = fmaf(h4.y, w[4*q+1], acc);
            acc = fmaf(h4.z, w[4*q+2], acc);
            acc = fmaf(h4.w, w[4*q+3], acc);
        }
        float a = (type == 2) ? fast_tanh(acc) : fast_sigmoid(acc);
        ash[k*4 + type] = a;
        __syncthreads();
        if (j < 128) {
            float4 v = *(const float4*)(ash + j*4);    // i,f,g,o
            c = fmaf(v.y, c, v.x * v.z);
            float h = v.w * fast_tanh(c);
            hsh[j] = h;
            const int t = dir ? (SEQ-1 - tq0 - step) : (tq0 + step);
            const size_t oi = ((size_t)t*NB + b)*256 + dir*128 + j;
            _Float16 hh = (_Float16)h;
            o1[oi] = hh;
            if constexpr (OMODE == 0) o2[oi] = (_Float16)(h - (float)hh);
        }
        __syncthreads();
        gcur = gnext;
    }
    if (j < 128) { st[j] = hsh[j]; st[128 + j] = c; }
}

// ---------------------------------------------------------------------------
// Head: y[m] = sum_j out1[m][j]*w_out[j] + b_out. One wave per row.
// ---------------------------------------------------------------------------
__global__ __launch_bounds__(256) void final_lin(
    const _Float16* __restrict__ out1,
    const float* __restrict__ wout, const float* __restrict__ bout,
    float* __restrict__ y)
{
    const int lane = threadIdx.x & 63;
    const int wave = threadIdx.x >> 6;
    const int row  = blockIdx.x * 4 + wave;
    f16x4 u = *(const f16x4*)(out1 + (size_t)row*256 + lane*4);
    float4 wv = *(const float4*)(wout + lane*4);
    float s = (float)u[0]*wv.x + (float)u[1]*wv.y + (float)u[2]*wv.z + (float)u[3]*wv.w;
    #pragma unroll
    for (int off = 32; off > 0; off >>= 1) s += __shfl_down(s, off, 64);
    if (lane == 0) y[row] = s + bout[0];
}

extern "C" void kernel_launch(void* const* d_in, const int* in_sizes, int n_in,
                              void* d_out, int out_size, void* d_ws, size_t ws_size,
                              hipStream_t stream) {
    const float* x      = (const float*)d_in[0];
    const float* wih_f0 = (const float*)d_in[1];
    const float* whh_f0 = (const float*)d_in[2];
    const float* b_f0   = (const float*)d_in[3];
    const float* wih_r0 = (const float*)d_in[4];
    const float* whh_r0 = (const float*)d_in[5];
    const float* b_r0   = (const float*)d_in[6];
    const float* wih_f1 = (const float*)d_in[7];
    const float* whh_f1 = (const float*)d_in[8];
    const float* b_f1   = (const float*)d_in[9];
    const float* wih_r1 = (const float*)d_in[10];
    const float* whh_r1 = (const float*)d_in[11];
    const float* b_r1   = (const float*)d_in[12];
    const float* w_out  = (const float*)d_in[13];
    const float* b_out  = (const float*)d_in[14];

    const size_t w0N = 512*64, w1N = (size_t)512*256;
    const size_t w0B = w0N*2, w1B = w1N*2;
    const size_t stB = 128*256*4;
    const size_t hB  = (size_t)SEQ*NB*256*2;     // 67.1 MB per f16 buffer
    const size_t fixedB = 4*w0B + 4*w1B + stB;   // ~1.44 MB

    const int cand[7] = {2048, 1024, 512, 256, 128, 64, 32};
    int Tc = 0; int tierA = 1;
    for (int i = 0; i < 7 && !Tc; ++i)
        if (fixedB + 3*hB + (size_t)cand[i]*NB*1024*4 <= ws_size) Tc = cand[i];
    if (!Tc) {
        tierA = 0;
        for (int i = 0; i < 7 && !Tc; ++i)
            if (fixedB + 2*hB + (size_t)cand[i]*NB*1024*4 <= ws_size) Tc = cand[i];
        if (!Tc) Tc = 32;  // forced minimum
    }
    const int nq = SEQ / Tc;

    char* p = (char*)d_ws;
    _Float16* whi0f = (_Float16*)p; p += w0B;
    _Float16* wlo0f = (_Float16*)p; p += w0B;
    _Float16* whi0r = (_Float16*)p; p += w0B;
    _Float16* wlo0r = (_Float16*)p; p += w0B;
    _Float16* whi1f = (_Float16*)p; p += w1B;
    _Float16* wlo1f = (_Float16*)p; p += w1B;
    _Float16* whi1r = (_Float16*)p; p += w1B;
    _Float16* wlo1r = (_Float16*)p; p += w1B;
    float*    state = (float*)p;    p += stB;
    _Float16* out1  = (_Float16*)p; p += hB;
    _Float16* h0hi  = (_Float16*)p; p += hB;
    _Float16* h0lo  = (_Float16*)p; if (tierA) p += hB;
    float*    gx    = (float*)p;

    // pre-split input weights f32 -> f16 hi/lo
    split_f32<<<(int)((w0N+255)/256), 256, 0, stream>>>(wih_f0, whi0f, wlo0f, (int)w0N);
    split_f32<<<(int)((w0N+255)/256), 256, 0, stream>>>(wih_r0, whi0r, wlo0r, (int)w0N);
    split_f32<<<(int)((w1N+255)/256), 256, 0, stream>>>(wih_f1, whi1f, wlo1f, (int)w1N);
    split_f32<<<(int)((w1N+255)/256), 256, 0, stream>>>(wih_r1, whi1r, wlo1r, (int)w1N);

    for (int q = 0; q < nq; ++q) {
        gemm0<<<dim3(8, Tc, 2), 256, 0, stream>>>(x, whi0f, wlo0f, whi0r, wlo0r,
                                                  b_f0, b_r0, gx, q*Tc);
        if (tierA)
            lstm_rec<0><<<dim3(NB,2), 512, 0, stream>>>(gx, whh_f0, whh_r0, h0hi, h0lo,
                                                        state, q*Tc, Tc, q==0);
        else
            lstm_rec<1><<<dim3(NB,2), 512, 0, stream>>>(gx, whh_f0, whh_r0, h0hi, nullptr,
                                                        state, q*Tc, Tc, q==0);
    }
    for (int q = 0; q < nq; ++q) {
        if (tierA)
            gemm1<1><<<dim3(8, Tc, 2), 256, 0, stream>>>(h0hi, h0lo, whi1f, wlo1f, whi1r, wlo1r,
                                                         b_f1, b_r1, gx, q*Tc);
        else
            gemm1<0><<<dim3(8, Tc, 2), 256, 0, stream>>>(h0hi, h0hi, whi1f, wlo1f, whi1r, wlo1r,
                                                         b_f1, b_r1, gx, q*Tc);
        lstm_rec<1><<<dim3(NB,2), 512, 0, stream>>>(gx, whh_f1, whh_r1, out1, nullptr,
                                                    state, q*Tc, Tc, q==0);
    }
    final_lin<<<SEQ*NB/4, 256, 0, stream>>>(out1, w_out, b_out, (float*)d_out);
}